// Round 5
// baseline (207.868 us; speedup 1.0000x reference)
//
#include <hip/hip_runtime.h>
#include <math.h>

#define NPTS 65536
#define NS   2048
#define C2   256
#define C3   128

// ---- workspace layout (byte offsets, all 16B aligned) ----
#define WS_XYZ2P   0          // (unused)                : 32768 B
#define WS_P2T     32768      // bf16 [2048][256]        : 1048576 B
#define WS_W0F     1081344    // bf16 frag [10][16][64][8] : 163840 B
#define WS_W1F     1245184    // bf16 frag [8][8][64][8]   : 65536 B
#define WS_AB0     1310720    // float A0[256],B0[256]   : 2048 B
#define WS_AB1     1312768    // float A1[128],B1[128]   : 1024 B
#define WS_KIDX    1313792    // int [65536][3]          : 786432 B
#define WS_KW      2100224    // float [65536][3]        : 786432 B
// total: 2886656 B

typedef __attribute__((ext_vector_type(8))) short bf16x8;
typedef __attribute__((ext_vector_type(4))) float f32x4;

__device__ __forceinline__ unsigned short f2bf(float f) {
  unsigned u = __builtin_bit_cast(unsigned, f);
  u = (u + 0x7FFFu + ((u >> 16) & 1u)) >> 16;
  return (unsigned short)u;
}
__device__ __forceinline__ float bf2f(unsigned h) {
  return __builtin_bit_cast(float, h << 16);
}

// =================== prep: tpose (blocks 0-127) + table packs ===================
__global__ __launch_bounds__(256) void pnfp_prep(
    const float* __restrict__ points2,
    const float* __restrict__ w0, const float* __restrict__ b0,
    const float* __restrict__ scale0, const float* __restrict__ bias0,
    const float* __restrict__ mean0, const float* __restrict__ var0,
    const float* __restrict__ w1, const float* __restrict__ b1,
    const float* __restrict__ scale1, const float* __restrict__ bias1,
    const float* __restrict__ mean1, const float* __restrict__ var1,
    unsigned char* __restrict__ ws)
{
  __shared__ float tile[64][65];
  const int tid = threadIdx.x;

  if (blockIdx.x < 128) {             // transpose points2 [256][2048]f32 -> [2048][256]bf16
    const int st = blockIdx.x & 31;   // s-tile
    const int dt = blockIdx.x >> 5;   // d-tile
#pragma unroll
    for (int it = 0; it < 16; ++it) {
      int j = it * 256 + tid;
      int d = j >> 6, s = j & 63;
      tile[d][s] = points2[(dt * 64 + d) * NS + st * 64 + s];
    }
    __syncthreads();
    unsigned short* p2t = (unsigned short*)(ws + WS_P2T);
#pragma unroll
    for (int it = 0; it < 16; ++it) {
      int j = it * 256 + tid;
      int s = j >> 6, d = j & 63;
      p2t[(st * 64 + s) * 256 + dt * 64 + d] = f2bf(tile[d][s]);
    }
    return;
  }

  int gid = (blockIdx.x - 128) * 256 + tid;
  if (gid < 81920) {                  // W0 -> fragment-linear bf16
    int i = gid & 7, l = (gid >> 3) & 63, c = (gid >> 9) & 15, ks = gid >> 13;
    int k = ks * 32 + (l >> 4) * 8 + i;
    int col = c * 16 + (l & 15);
    ((unsigned short*)(ws + WS_W0F))[gid] = f2bf(w0[k * C2 + col]);
    return;
  }
  gid -= 81920;
  if (gid < 32768) {                  // W1 -> fragment-linear bf16
    int i = gid & 7, l = (gid >> 3) & 63, c = (gid >> 9) & 7, ks = gid >> 12;
    int k = ks * 32 + (l >> 4) * 8 + i;
    int col = c * 16 + (l & 15);
    ((unsigned short*)(ws + WS_W1F))[gid] = f2bf(w1[k * C3 + col]);
    return;
  }
  gid -= 32768;
  if (gid < 256) {                    // fused conv-bias + BN affine, layer 0
    float a = scale0[gid] / sqrtf(var0[gid] + 1e-5f);
    float bb = (b0[gid] - mean0[gid]) * a + bias0[gid];
    float* ab = (float*)(ws + WS_AB0);
    ab[gid] = a; ab[256 + gid] = bb;
    return;
  }
  gid -= 256;
  if (gid < 128) {                    // layer 1
    float a = scale1[gid] / sqrtf(var1[gid] + 1e-5f);
    float bb = (b1[gid] - mean1[gid]) * a + bias1[gid];
    float* ab = (float*)(ws + WS_AB1);
    ab[gid] = a; ab[128 + gid] = bb;
  }
}

// =================== KNN: top-3 of 2048 per point ===================
// T=8 ranks per point-group, P=2 points per thread, 64 points/block,
// grid 1024 (4 blocks/CU -> 16 waves/CU). Centres staged to LDS with |c|^2,
// strips stride-257 float4 (conflict-free, measured 0). Unconditional insert:
// values exact via fmin+2*med3; indices via strict-< cndmask chain (ties keep
// earlier = lower index, matching top_k). Merge consumed at rank 0 only,
// whose chain always merges lower-index-own lists (tie rule preserved).
__global__ __launch_bounds__(256) void pnfp_knn(
    const float* __restrict__ xyz1, const float* __restrict__ xyz2,
    unsigned char* __restrict__ ws)
{
  __shared__ float4 cs[2056];         // 8 strips * 257
  for (int j = threadIdx.x; j < NS; j += 256) {
    float x = xyz2[j], y = xyz2[NS + j], z = xyz2[2 * NS + j];
    float sc;
    {
#pragma clang fp contract(off)
      sc = (x * x + y * y) + z * z;
    }
    cs[j + (j >> 8)] = make_float4(x, y, z, sc);
  }
  __syncthreads();

  const int tid = threadIdx.x;
  const int rank = tid & 7;
  const int set = tid >> 3;                       // 32 sets/block
  const int nb = blockIdx.x * 64 + set * 2;       // 2 points per thread

  float px[2], py[2], pz[2], ps[2];
#pragma unroll
  for (int p = 0; p < 2; ++p) {
    int n = nb + p;
    px[p] = xyz1[n]; py[p] = xyz1[NPTS + n]; pz[p] = xyz1[2 * NPTS + n];
    {
#pragma clang fp contract(off)
      ps[p] = (px[p] * px[p] + py[p] * py[p]) + pz[p] * pz[p];
    }
  }

  float D0[2], D1[2], D2[2];
  int I0[2], I1[2], I2[2];
#pragma unroll
  for (int p = 0; p < 2; ++p) {
    D0[p] = 1e30f; D1[p] = 1e30f; D2[p] = 1e30f;
    I0[p] = 0; I1[p] = 0; I2[p] = 0;
  }

  const float4* cq = cs + rank * 257;
  const int sbase = rank << 8;
#pragma unroll 4
  for (int t = 0; t < 256; ++t) {
    const float4 c = cq[t];
    const int s = sbase + t;
#pragma unroll
    for (int p = 0; p < 2; ++p) {
      float dot = fmaf(pz[p], c.z, fmaf(py[p], c.y, px[p] * c.x));
      float d = (ps[p] + c.w) - 2.0f * dot;
      const bool c2 = d < D2[p], c1 = d < D1[p], c0 = d < D0[p];
      I2[p] = c2 ? (c1 ? I1[p] : s) : I2[p];
      I1[p] = c1 ? (c0 ? I0[p] : s) : I1[p];
      I0[p] = c0 ? s : I0[p];
      float n1 = __builtin_amdgcn_fmed3f(D0[p], D1[p], d);
      float n2 = __builtin_amdgcn_fmed3f(D1[p], D2[p], d);
      D0[p] = fminf(D0[p], d);
      D1[p] = n1; D2[p] = n2;
    }
  }

  // 3 merge stages (xor 1,2,4). Strict '<' prefers OWN list on ties; results
  // consumed at rank 0, whose chain always merges lower-index-own lists.
#pragma unroll
  for (int p = 0; p < 2; ++p) {
#pragma unroll
    for (int m = 1; m <= 4; m <<= 1) {
      float e0 = __shfl_xor(D0[p], m), e1 = __shfl_xor(D1[p], m), e2 = __shfl_xor(D2[p], m);
      int  j0 = __shfl_xor(I0[p], m), j1 = __shfl_xor(I1[p], m), j2 = __shfl_xor(I2[p], m);
      bool t0 = e0 < D0[p];
      float r0 = t0 ? e0 : D0[p]; int ri0 = t0 ? j0 : I0[p];
      float X0 = t0 ? D0[p] : D1[p], X1 = t0 ? D1[p] : D2[p];
      int  XI0 = t0 ? I0[p] : I1[p], XI1 = t0 ? I1[p] : I2[p];
      float Y0 = t0 ? e1 : e0, Y1v = t0 ? e2 : e1;
      int  YJ0 = t0 ? j1 : j0, YJ1 = t0 ? j2 : j1;
      bool t1 = Y0 < X0;
      float r1 = t1 ? Y0 : X0; int ri1 = t1 ? YJ0 : XI0;
      float X0b = t1 ? X0 : X1; int XI0b = t1 ? XI0 : XI1;
      float Y0b = t1 ? Y1v : Y0; int YJ0b = t1 ? YJ1 : YJ0;
      bool t2 = Y0b < X0b;
      float r2 = t2 ? Y0b : X0b; int ri2 = t2 ? YJ0b : XI0b;
      D0[p] = r0; D1[p] = r1; D2[p] = r2; I0[p] = ri0; I1[p] = ri1; I2[p] = ri2;
    }
  }

  if (rank == 0) {
#pragma unroll
    for (int p = 0; p < 2; ++p) {
      const int n = nb + p;
      float q0 = 1.0f / (D0[p] + 1e-8f);
      float q1 = 1.0f / (D1[p] + 1e-8f);
      float q2 = 1.0f / (D2[p] + 1e-8f);
      float qs = (q0 + q1) + q2;
      int* oi = (int*)(ws + WS_KIDX) + 3 * n;
      float* owp = (float*)(ws + WS_KW) + 3 * n;
      oi[0] = I0[p]; oi[1] = I1[p]; oi[2] = I2[p];
      owp[0] = q0 / qs; owp[1] = q1 / qs; owp[2] = q2 / qs;
    }
  }
}

// =================== fused interp + concat + MLP (unchanged) ===================
__global__ __launch_bounds__(256, 3) void pnfp_fused(
    const float* __restrict__ points1,
    const unsigned char* __restrict__ ws,
    float* __restrict__ out)
{
  __shared__ __align__(16) unsigned char smem[41984];
  unsigned short* Fh = (unsigned short*)smem;                 // [64][328] bf16
  const unsigned short* p2t = (const unsigned short*)(ws + WS_P2T);
  const unsigned short* w0f = (const unsigned short*)(ws + WS_W0F);
  const unsigned short* w1f = (const unsigned short*)(ws + WS_W1F);
  const float* ab0 = (const float*)(ws + WS_AB0);
  const float* ab1 = (const float*)(ws + WS_AB1);
  const int* kidx = (const int*)(ws + WS_KIDX);
  const float* kw = (const float*)(ws + WS_KW);

  const int tid = threadIdx.x;
  const int wv = tid >> 6, lane = tid & 63;
  const int n0 = blockIdx.x * 64;

  // ---- F part 1: points1^T (cols 0..63)
#pragma unroll
  for (int it = 0; it < 16; ++it) {
    int j = tid + it * 256;
    int d = j >> 6, r = j & 63;
    Fh[r * 328 + d] = f2bf(points1[d * NPTS + n0 + r]);
  }
  // ---- F part 2: 3-NN weighted interpolation (cols 64..319)
  {
    const int dbase = lane * 4;
#pragma unroll 2
    for (int rr = 0; rr < 16; ++rr) {
      const int r = wv * 16 + rr, n = n0 + r;
      const int a0 = kidx[3 * n], a1 = kidx[3 * n + 1], a2 = kidx[3 * n + 2];
      const float w0 = kw[3 * n], w1 = kw[3 * n + 1], w2 = kw[3 * n + 2];
      uint2 u0 = *(const uint2*)(p2t + a0 * 256 + dbase);
      uint2 u1 = *(const uint2*)(p2t + a1 * 256 + dbase);
      uint2 u2 = *(const uint2*)(p2t + a2 * 256 + dbase);
      float f0 = fmaf(w2, bf2f(u2.x & 0xFFFFu), fmaf(w1, bf2f(u1.x & 0xFFFFu), w0 * bf2f(u0.x & 0xFFFFu)));
      float f1 = fmaf(w2, bf2f(u2.x >> 16),     fmaf(w1, bf2f(u1.x >> 16),     w0 * bf2f(u0.x >> 16)));
      float f2v = fmaf(w2, bf2f(u2.y & 0xFFFFu), fmaf(w1, bf2f(u1.y & 0xFFFFu), w0 * bf2f(u0.y & 0xFFFFu)));
      float f3 = fmaf(w2, bf2f(u2.y >> 16),     fmaf(w1, bf2f(u1.y >> 16),     w0 * bf2f(u0.y >> 16)));
      uint2 pk;
      pk.x = (unsigned)f2bf(f0) | ((unsigned)f2bf(f1) << 16);
      pk.y = (unsigned)f2bf(f2v) | ((unsigned)f2bf(f3) << 16);
      *(uint2*)(Fh + r * 328 + 64 + dbase) = pk;
    }
  }
  __syncthreads();

  // ---- GEMM1: [64,320] x [320,256], wave w -> cols [w*64, w*64+64)
  f32x4 zero4 = {0.f, 0.f, 0.f, 0.f};
  f32x4 acc[4][4];
#pragma unroll
  for (int a = 0; a < 4; ++a)
#pragma unroll
    for (int b = 0; b < 4; ++b) acc[a][b] = zero4;

  const int arow = lane & 15;
  const int koff = (lane >> 4) * 8;
  bf16x8 bcur[4], bnxt[4];
#pragma unroll
  for (int ct = 0; ct < 4; ++ct)
    bcur[ct] = *(const bf16x8*)(w0f + ((wv * 4 + ct) * 64 + lane) * 8);
  for (int ks = 0; ks < 10; ++ks) {
#pragma unroll
    for (int ct = 0; ct < 4; ++ct)
      bnxt[ct] = *(const bf16x8*)(w0f + (((ks + 1) * 16 + wv * 4 + ct) * 64 + lane) * 8);
    bf16x8 af[4];
#pragma unroll
    for (int rt = 0; rt < 4; ++rt)
      af[rt] = *(const bf16x8*)(Fh + (rt * 16 + arow) * 328 + ks * 32 + koff);
#pragma unroll
    for (int ct = 0; ct < 4; ++ct)
#pragma unroll
      for (int rt = 0; rt < 4; ++rt)
        acc[rt][ct] = __builtin_amdgcn_mfma_f32_16x16x32_bf16(af[rt], bcur[ct], acc[rt][ct], 0, 0, 0);
#pragma unroll
    for (int ct = 0; ct < 4; ++ct) bcur[ct] = bnxt[ct];
  }
  __syncthreads();

  // ---- BN+ReLU -> Y1 bf16 [64][264] (reuses smem)
  unsigned short* Y1 = (unsigned short*)smem;
#pragma unroll
  for (int ct = 0; ct < 4; ++ct) {
    const int c = wv * 64 + ct * 16 + arow;
    const float a = ab0[c], b = ab0[256 + c];
#pragma unroll
    for (int rt = 0; rt < 4; ++rt) {
      const int rbase = rt * 16 + (lane >> 4) * 4;
#pragma unroll
      for (int qi = 0; qi < 4; ++qi) {
        float yv = fmaxf(fmaf(acc[rt][ct][qi], a, b), 0.0f);
        Y1[(rbase + qi) * 264 + c] = f2bf(yv);
      }
    }
  }
  __syncthreads();

  // ---- GEMM2: [64,256] x [256,128], wave w -> cols [w*32, w*32+32)
  f32x4 acc2[4][2];
#pragma unroll
  for (int a = 0; a < 4; ++a) { acc2[a][0] = zero4; acc2[a][1] = zero4; }
  bf16x8 b2cur[2], b2nxt[2];
#pragma unroll
  for (int ct = 0; ct < 2; ++ct)
    b2cur[ct] = *(const bf16x8*)(w1f + ((wv * 2 + ct) * 64 + lane) * 8);
  for (int ks = 0; ks < 8; ++ks) {
#pragma unroll
    for (int ct = 0; ct < 2; ++ct)
      b2nxt[ct] = *(const bf16x8*)(w1f + (((ks + 1) * 8 + wv * 2 + ct) * 64 + lane) * 8);
    bf16x8 af[4];
#pragma unroll
    for (int rt = 0; rt < 4; ++rt)
      af[rt] = *(const bf16x8*)(Y1 + (rt * 16 + arow) * 264 + ks * 32 + koff);
#pragma unroll
    for (int ct = 0; ct < 2; ++ct)
#pragma unroll
      for (int rt = 0; rt < 4; ++rt)
        acc2[rt][ct] = __builtin_amdgcn_mfma_f32_16x16x32_bf16(af[rt], b2cur[ct], acc2[rt][ct], 0, 0, 0);
#pragma unroll
    for (int ct = 0; ct < 2; ++ct) b2cur[ct] = b2nxt[ct];
  }
  __syncthreads();

  // ---- BN+ReLU -> OUT f32 [128][67] in LDS, then coalesced global store
  float* OUT = (float*)smem;
#pragma unroll
  for (int ct = 0; ct < 2; ++ct) {
    const int c = wv * 32 + ct * 16 + arow;
    const float a = ab1[c], b = ab1[128 + c];
#pragma unroll
    for (int rt = 0; rt < 4; ++rt) {
      const int rbase = rt * 16 + (lane >> 4) * 4;
#pragma unroll
      for (int qi = 0; qi < 4; ++qi)
        OUT[c * 67 + rbase + qi] = fmaxf(fmaf(acc2[rt][ct][qi], a, b), 0.0f);
    }
  }
  __syncthreads();
#pragma unroll
  for (int it = 0; it < 32; ++it) {
    int j = tid + it * 256;
    int c = j >> 6, n = j & 63;
    out[c * NPTS + n0 + n] = OUT[c * 67 + n];
  }
}

// =================== host launcher ===================
extern "C" void kernel_launch(void* const* d_in, const int* in_sizes, int n_in,
                              void* d_out, int out_size, void* d_ws, size_t ws_size,
                              hipStream_t stream) {
  (void)in_sizes; (void)n_in; (void)out_size; (void)ws_size;
  const float* xyz1    = (const float*)d_in[0];
  const float* xyz2    = (const float*)d_in[1];
  const float* points1 = (const float*)d_in[2];
  const float* points2 = (const float*)d_in[3];
  const float* w0      = (const float*)d_in[4];
  const float* b0      = (const float*)d_in[5];
  const float* scale0  = (const float*)d_in[6];
  const float* bias0   = (const float*)d_in[7];
  const float* mean0   = (const float*)d_in[8];
  const float* var0    = (const float*)d_in[9];
  const float* w1      = (const float*)d_in[10];
  const float* b1      = (const float*)d_in[11];
  const float* scale1  = (const float*)d_in[12];
  const float* bias1   = (const float*)d_in[13];
  const float* mean1   = (const float*)d_in[14];
  const float* var1    = (const float*)d_in[15];
  unsigned char* ws = (unsigned char*)d_ws;
  float* out = (float*)d_out;

  pnfp_prep<<<578, 256, 0, stream>>>(points2, w0, b0, scale0, bias0, mean0, var0,
                                     w1, b1, scale1, bias1, mean1, var1, ws);
  pnfp_knn<<<1024, 256, 0, stream>>>(xyz1, xyz2, ws);
  pnfp_fused<<<1024, 256, 0, stream>>>(points1, ws, out);
}

// Round 6
// 204.902 us; speedup vs baseline: 1.0145x; 1.0145x over previous
//
#include <hip/hip_runtime.h>
#include <math.h>

#define NPTS 65536
#define NS   2048
#define C2   256
#define C3   128

// ---- workspace layout (byte offsets, all 16B aligned) ----
#define WS_P2T     32768      // bf16 [2048][256]        : 1048576 B
#define WS_W0F     1081344    // bf16 frag [10][16][64][8] : 163840 B
#define WS_W1F     1245184    // bf16 frag [8][8][64][8]   : 65536 B
#define WS_AB0     1310720    // float A0[256],B0[256]   : 2048 B
#define WS_AB1     1312768    // float A1[128],B1[128]   : 1024 B
#define WS_KIDX    1313792    // int [65536][3]          : 786432 B
#define WS_KW      2100224    // float [65536][3]        : 786432 B

typedef __attribute__((ext_vector_type(8))) short bf16x8;
typedef __attribute__((ext_vector_type(4))) float f32x4;

__device__ __forceinline__ unsigned short f2bf(float f) {
  unsigned u = __builtin_bit_cast(unsigned, f);
  u = (u + 0x7FFFu + ((u >> 16) & 1u)) >> 16;
  return (unsigned short)u;
}
__device__ __forceinline__ float bf2f(unsigned h) {
  return __builtin_bit_cast(float, h << 16);
}

// =================== KNN (blocks 0..1023) + prep (blocks 1024..1601) ===================
// KNN: T=16 ranks/point-group, P=4 points/thread, 64 pts/block, 4 blocks/CU.
// Strips of 128 centres, stride 129 float4 (2-way bank alias on b128 = free).
// Per-eval math identical to the version passing rounds 1-5 (exact d, strict-<
// insert, med3/min value updates). 4-stage shfl merge, consumed at rank 0
// (own list always lower-index strips -> top_k tie rule preserved).
__global__ __launch_bounds__(256) void pnfp_knn(
    const float* __restrict__ xyz1, const float* __restrict__ xyz2,
    const float* __restrict__ points2,
    const float* __restrict__ w0, const float* __restrict__ b0,
    const float* __restrict__ scale0, const float* __restrict__ bias0,
    const float* __restrict__ mean0, const float* __restrict__ var0,
    const float* __restrict__ w1, const float* __restrict__ b1,
    const float* __restrict__ scale1, const float* __restrict__ bias1,
    const float* __restrict__ mean1, const float* __restrict__ var1,
    unsigned char* __restrict__ ws)
{
  __shared__ __align__(16) unsigned char kns[33024];
  const int tid = threadIdx.x;

  if (blockIdx.x >= 1024) {           // ---------------- prep path ----------------
    const int pbid = blockIdx.x - 1024;
    if (pbid < 128) {                 // transpose points2 [256][2048]f32 -> [2048][256]bf16
      float (*tile)[65] = (float(*)[65])kns;
      const int st = pbid & 31, dt = pbid >> 5;
#pragma unroll
      for (int it = 0; it < 16; ++it) {
        int j = it * 256 + tid;
        int d = j >> 6, s = j & 63;
        tile[d][s] = points2[(dt * 64 + d) * NS + st * 64 + s];
      }
      __syncthreads();
      unsigned short* p2t = (unsigned short*)(ws + WS_P2T);
#pragma unroll
      for (int it = 0; it < 16; ++it) {
        int j = it * 256 + tid;
        int s = j >> 6, d = j & 63;
        p2t[(st * 64 + s) * 256 + dt * 64 + d] = f2bf(tile[d][s]);
      }
      return;
    }
    int gid = (pbid - 128) * 256 + tid;
    if (gid < 81920) {                // W0 -> fragment-linear bf16
      int i = gid & 7, l = (gid >> 3) & 63, c = (gid >> 9) & 15, ks = gid >> 13;
      int k = ks * 32 + (l >> 4) * 8 + i;
      int col = c * 16 + (l & 15);
      ((unsigned short*)(ws + WS_W0F))[gid] = f2bf(w0[k * C2 + col]);
      return;
    }
    gid -= 81920;
    if (gid < 32768) {                // W1 -> fragment-linear bf16
      int i = gid & 7, l = (gid >> 3) & 63, c = (gid >> 9) & 7, ks = gid >> 12;
      int k = ks * 32 + (l >> 4) * 8 + i;
      int col = c * 16 + (l & 15);
      ((unsigned short*)(ws + WS_W1F))[gid] = f2bf(w1[k * C3 + col]);
      return;
    }
    gid -= 32768;
    if (gid < 256) {                  // fused conv-bias + BN affine, layer 0
      float a = scale0[gid] / sqrtf(var0[gid] + 1e-5f);
      float bb = (b0[gid] - mean0[gid]) * a + bias0[gid];
      float* ab = (float*)(ws + WS_AB0);
      ab[gid] = a; ab[256 + gid] = bb;
      return;
    }
    gid -= 256;
    if (gid < 128) {                  // layer 1
      float a = scale1[gid] / sqrtf(var1[gid] + 1e-5f);
      float bb = (b1[gid] - mean1[gid]) * a + bias1[gid];
      float* ab = (float*)(ws + WS_AB1);
      ab[gid] = a; ab[128 + gid] = bb;
    }
    return;
  }

  // ---------------- KNN path ----------------
  float4* cs = (float4*)kns;          // 16 strips * 129
  for (int j = tid; j < NS; j += 256) {
    float x = xyz2[j], y = xyz2[NS + j], z = xyz2[2 * NS + j];
    float sc;
    {
#pragma clang fp contract(off)
      sc = (x * x + y * y) + z * z;
    }
    cs[(j >> 7) * 129 + (j & 127)] = make_float4(x, y, z, sc);
  }
  __syncthreads();

  const int rank = tid & 15;
  const int set = tid >> 4;                       // 16 sets/block
  const int nb = blockIdx.x * 64 + set * 4;       // 4 points per thread

  float px[4], py[4], pz[4], ps[4];
#pragma unroll
  for (int p = 0; p < 4; ++p) {
    int n = nb + p;
    px[p] = xyz1[n]; py[p] = xyz1[NPTS + n]; pz[p] = xyz1[2 * NPTS + n];
    {
#pragma clang fp contract(off)
      ps[p] = (px[p] * px[p] + py[p] * py[p]) + pz[p] * pz[p];
    }
  }

  float D0[4], D1[4], D2[4];
  int I0[4], I1[4], I2[4];
#pragma unroll
  for (int p = 0; p < 4; ++p) {
    D0[p] = 1e30f; D1[p] = 1e30f; D2[p] = 1e30f;
    I0[p] = 0; I1[p] = 0; I2[p] = 0;
  }

  const float4* cq = cs + rank * 129;
  const int sbase = rank << 7;
#pragma unroll 4
  for (int t = 0; t < 128; ++t) {
    const float4 c = cq[t];
    const int s = sbase + t;
#pragma unroll
    for (int p = 0; p < 4; ++p) {
      float dot = fmaf(pz[p], c.z, fmaf(py[p], c.y, px[p] * c.x));
      float d = (ps[p] + c.w) - 2.0f * dot;
      const bool c2 = d < D2[p], c1 = d < D1[p], c0 = d < D0[p];
      I2[p] = c2 ? (c1 ? I1[p] : s) : I2[p];
      I1[p] = c1 ? (c0 ? I0[p] : s) : I1[p];
      I0[p] = c0 ? s : I0[p];
      float n1 = __builtin_amdgcn_fmed3f(D0[p], D1[p], d);
      float n2 = __builtin_amdgcn_fmed3f(D1[p], D2[p], d);
      D0[p] = fminf(D0[p], d);
      D1[p] = n1; D2[p] = n2;
    }
  }

  // 4 merge stages (xor 1,2,4,8) within the 16-rank group.
#pragma unroll
  for (int p = 0; p < 4; ++p) {
#pragma unroll
    for (int m = 1; m <= 8; m <<= 1) {
      float e0 = __shfl_xor(D0[p], m), e1 = __shfl_xor(D1[p], m), e2 = __shfl_xor(D2[p], m);
      int  j0 = __shfl_xor(I0[p], m), j1 = __shfl_xor(I1[p], m), j2 = __shfl_xor(I2[p], m);
      bool t0 = e0 < D0[p];
      float r0 = t0 ? e0 : D0[p]; int ri0 = t0 ? j0 : I0[p];
      float X0 = t0 ? D0[p] : D1[p], X1 = t0 ? D1[p] : D2[p];
      int  XI0 = t0 ? I0[p] : I1[p], XI1 = t0 ? I1[p] : I2[p];
      float Y0 = t0 ? e1 : e0, Y1v = t0 ? e2 : e1;
      int  YJ0 = t0 ? j1 : j0, YJ1 = t0 ? j2 : j1;
      bool t1 = Y0 < X0;
      float r1 = t1 ? Y0 : X0; int ri1 = t1 ? YJ0 : XI0;
      float X0b = t1 ? X0 : X1; int XI0b = t1 ? XI0 : XI1;
      float Y0b = t1 ? Y1v : Y0; int YJ0b = t1 ? YJ1 : YJ0;
      bool t2 = Y0b < X0b;
      float r2 = t2 ? Y0b : X0b; int ri2 = t2 ? YJ0b : XI0b;
      D0[p] = r0; D1[p] = r1; D2[p] = r2; I0[p] = ri0; I1[p] = ri1; I2[p] = ri2;
    }
  }

  if (rank == 0) {
#pragma unroll
    for (int p = 0; p < 4; ++p) {
      const int n = nb + p;
      float q0 = 1.0f / (D0[p] + 1e-8f);
      float q1 = 1.0f / (D1[p] + 1e-8f);
      float q2 = 1.0f / (D2[p] + 1e-8f);
      float qs = (q0 + q1) + q2;
      int* oi = (int*)(ws + WS_KIDX) + 3 * n;
      float* owp = (float*)(ws + WS_KW) + 3 * n;
      oi[0] = I0[p]; oi[1] = I1[p]; oi[2] = I2[p];
      owp[0] = q0 / qs; owp[1] = q1 / qs; owp[2] = q2 / qs;
    }
  }
}

// =================== fused interp + concat + MLP ===================
// BM=64 points/block, 256 threads (4 waves). kidx/kw preloaded to LDS so the
// interp gathers issue with no serial global dependency.
__global__ __launch_bounds__(256, 3) void pnfp_fused(
    const float* __restrict__ points1,
    const unsigned char* __restrict__ ws,
    float* __restrict__ out)
{
  __shared__ __align__(16) unsigned char smem[43520];
  unsigned short* Fh = (unsigned short*)smem;                 // [64][328] bf16
  int*   kI = (int*)(smem + 41984);                           // [192]
  float* kW = (float*)(smem + 42752);                         // [192]
  const unsigned short* p2t = (const unsigned short*)(ws + WS_P2T);
  const unsigned short* w0f = (const unsigned short*)(ws + WS_W0F);
  const unsigned short* w1f = (const unsigned short*)(ws + WS_W1F);
  const float* ab0 = (const float*)(ws + WS_AB0);
  const float* ab1 = (const float*)(ws + WS_AB1);
  const int* kidx = (const int*)(ws + WS_KIDX);
  const float* kw = (const float*)(ws + WS_KW);

  const int tid = threadIdx.x;
  const int wv = tid >> 6, lane = tid & 63;
  const int n0 = blockIdx.x * 64;

  // ---- preload kidx/kw for the block's 64 points
  if (tid < 192) {
    kI[tid] = kidx[3 * n0 + tid];
    kW[tid] = kw[3 * n0 + tid];
  }
  // ---- F part 1: points1^T (cols 0..63)
#pragma unroll
  for (int it = 0; it < 16; ++it) {
    int j = tid + it * 256;
    int d = j >> 6, r = j & 63;
    Fh[r * 328 + d] = f2bf(points1[d * NPTS + n0 + r]);
  }
  __syncthreads();
  // ---- F part 2: 3-NN weighted interpolation (cols 64..319)
  {
    const int dbase = lane * 4;
#pragma unroll 4
    for (int rr = 0; rr < 16; ++rr) {
      const int r = wv * 16 + rr;
      const int a0 = kI[3 * r], a1 = kI[3 * r + 1], a2 = kI[3 * r + 2];
      const float w0 = kW[3 * r], w1 = kW[3 * r + 1], w2 = kW[3 * r + 2];
      uint2 u0 = *(const uint2*)(p2t + a0 * 256 + dbase);
      uint2 u1 = *(const uint2*)(p2t + a1 * 256 + dbase);
      uint2 u2 = *(const uint2*)(p2t + a2 * 256 + dbase);
      float f0 = fmaf(w2, bf2f(u2.x & 0xFFFFu), fmaf(w1, bf2f(u1.x & 0xFFFFu), w0 * bf2f(u0.x & 0xFFFFu)));
      float f1 = fmaf(w2, bf2f(u2.x >> 16),     fmaf(w1, bf2f(u1.x >> 16),     w0 * bf2f(u0.x >> 16)));
      float f2v = fmaf(w2, bf2f(u2.y & 0xFFFFu), fmaf(w1, bf2f(u1.y & 0xFFFFu), w0 * bf2f(u0.y & 0xFFFFu)));
      float f3 = fmaf(w2, bf2f(u2.y >> 16),     fmaf(w1, bf2f(u1.y >> 16),     w0 * bf2f(u0.y >> 16)));
      uint2 pk;
      pk.x = (unsigned)f2bf(f0) | ((unsigned)f2bf(f1) << 16);
      pk.y = (unsigned)f2bf(f2v) | ((unsigned)f2bf(f3) << 16);
      *(uint2*)(Fh + r * 328 + 64 + dbase) = pk;
    }
  }
  __syncthreads();

  // ---- GEMM1: [64,320] x [320,256], wave w -> cols [w*64, w*64+64)
  f32x4 zero4 = {0.f, 0.f, 0.f, 0.f};
  f32x4 acc[4][4];
#pragma unroll
  for (int a = 0; a < 4; ++a)
#pragma unroll
    for (int b = 0; b < 4; ++b) acc[a][b] = zero4;

  const int arow = lane & 15;
  const int koff = (lane >> 4) * 8;
  bf16x8 bcur[4], bnxt[4];
#pragma unroll
  for (int ct = 0; ct < 4; ++ct)
    bcur[ct] = *(const bf16x8*)(w0f + ((wv * 4 + ct) * 64 + lane) * 8);
  for (int ks = 0; ks < 10; ++ks) {
    // prefetch next K-step's B fragments (ks=9 reads into W1F region: in-bounds, unused)
#pragma unroll
    for (int ct = 0; ct < 4; ++ct)
      bnxt[ct] = *(const bf16x8*)(w0f + (((ks + 1) * 16 + wv * 4 + ct) * 64 + lane) * 8);
    bf16x8 af[4];
#pragma unroll
    for (int rt = 0; rt < 4; ++rt)
      af[rt] = *(const bf16x8*)(Fh + (rt * 16 + arow) * 328 + ks * 32 + koff);
#pragma unroll
    for (int ct = 0; ct < 4; ++ct)
#pragma unroll
      for (int rt = 0; rt < 4; ++rt)
        acc[rt][ct] = __builtin_amdgcn_mfma_f32_16x16x32_bf16(af[rt], bcur[ct], acc[rt][ct], 0, 0, 0);
#pragma unroll
    for (int ct = 0; ct < 4; ++ct) bcur[ct] = bnxt[ct];
  }
  __syncthreads();

  // ---- BN+ReLU -> Y1 bf16 [64][264] (reuses smem)
  unsigned short* Y1 = (unsigned short*)smem;
#pragma unroll
  for (int ct = 0; ct < 4; ++ct) {
    const int c = wv * 64 + ct * 16 + arow;
    const float a = ab0[c], b = ab0[256 + c];
#pragma unroll
    for (int rt = 0; rt < 4; ++rt) {
      const int rbase = rt * 16 + (lane >> 4) * 4;
#pragma unroll
      for (int qi = 0; qi < 4; ++qi) {
        float yv = fmaxf(fmaf(acc[rt][ct][qi], a, b), 0.0f);
        Y1[(rbase + qi) * 264 + c] = f2bf(yv);
      }
    }
  }
  __syncthreads();

  // ---- GEMM2: [64,256] x [256,128], wave w -> cols [w*32, w*32+32)
  f32x4 acc2[4][2];
#pragma unroll
  for (int a = 0; a < 4; ++a) { acc2[a][0] = zero4; acc2[a][1] = zero4; }
  bf16x8 b2cur[2], b2nxt[2];
#pragma unroll
  for (int ct = 0; ct < 2; ++ct)
    b2cur[ct] = *(const bf16x8*)(w1f + ((wv * 2 + ct) * 64 + lane) * 8);
  for (int ks = 0; ks < 8; ++ks) {
#pragma unroll
    for (int ct = 0; ct < 2; ++ct)
      b2nxt[ct] = *(const bf16x8*)(w1f + (((ks + 1) * 8 + wv * 2 + ct) * 64 + lane) * 8);
    bf16x8 af[4];
#pragma unroll
    for (int rt = 0; rt < 4; ++rt)
      af[rt] = *(const bf16x8*)(Y1 + (rt * 16 + arow) * 264 + ks * 32 + koff);
#pragma unroll
    for (int ct = 0; ct < 2; ++ct)
#pragma unroll
      for (int rt = 0; rt < 4; ++rt)
        acc2[rt][ct] = __builtin_amdgcn_mfma_f32_16x16x32_bf16(af[rt], b2cur[ct], acc2[rt][ct], 0, 0, 0);
#pragma unroll
    for (int ct = 0; ct < 2; ++ct) b2cur[ct] = b2nxt[ct];
  }
  __syncthreads();

  // ---- BN+ReLU -> OUT f32 [128][67] in LDS, then coalesced global store
  float* OUT = (float*)smem;
#pragma unroll
  for (int ct = 0; ct < 2; ++ct) {
    const int c = wv * 32 + ct * 16 + arow;
    const float a = ab1[c], b = ab1[128 + c];
#pragma unroll
    for (int rt = 0; rt < 4; ++rt) {
      const int rbase = rt * 16 + (lane >> 4) * 4;
#pragma unroll
      for (int qi = 0; qi < 4; ++qi)
        OUT[c * 67 + rbase + qi] = fmaxf(fmaf(acc2[rt][ct][qi], a, b), 0.0f);
    }
  }
  __syncthreads();
#pragma unroll
  for (int it = 0; it < 32; ++it) {
    int j = tid + it * 256;
    int c = j >> 6, n = j & 63;
    out[c * NPTS + n0 + n] = OUT[c * 67 + n];
  }
}

// =================== host launcher ===================
extern "C" void kernel_launch(void* const* d_in, const int* in_sizes, int n_in,
                              void* d_out, int out_size, void* d_ws, size_t ws_size,
                              hipStream_t stream) {
  (void)in_sizes; (void)n_in; (void)out_size; (void)ws_size;
  const float* xyz1    = (const float*)d_in[0];
  const float* xyz2    = (const float*)d_in[1];
  const float* points1 = (const float*)d_in[2];
  const float* points2 = (const float*)d_in[3];
  const float* w0      = (const float*)d_in[4];
  const float* b0      = (const float*)d_in[5];
  const float* scale0  = (const float*)d_in[6];
  const float* bias0   = (const float*)d_in[7];
  const float* mean0   = (const float*)d_in[8];
  const float* var0    = (const float*)d_in[9];
  const float* w1      = (const float*)d_in[10];
  const float* b1      = (const float*)d_in[11];
  const float* scale1  = (const float*)d_in[12];
  const float* bias1   = (const float*)d_in[13];
  const float* mean1   = (const float*)d_in[14];
  const float* var1    = (const float*)d_in[15];
  unsigned char* ws = (unsigned char*)d_ws;
  float* out = (float*)d_out;

  pnfp_knn<<<1602, 256, 0, stream>>>(xyz1, xyz2, points2,
                                     w0, b0, scale0, bias0, mean0, var0,
                                     w1, b1, scale1, bias1, mean1, var1, ws);
  pnfp_fused<<<1024, 256, 0, stream>>>(points1, ws, out);
}